// Round 9
// baseline (247.521 us; speedup 1.0000x reference)
//
#include <hip/hip_runtime.h>
#include <hip/hip_bf16.h>

#define BB 4
#define SEQ 2048
#define NH 4
#define D 64
#define NPAIR 16
#define HOUT 8
#define LOSS_BASE ((size_t)BB * SEQ * HOUT * D)

// ---- float ws layout ----
#define OFF_PART 0                              // part[8][16][3][4096]
#define N_PART   (8 * 16 * 3 * 4096)
#define OFF_SPART (OFF_PART + N_PART)           // Spart[16][32][64]
#define N_SPART  (16 * 32 * 64)
#define OFF_US   (OFF_SPART + N_SPART)
// ushort arrays, each 16*2048*64: 0 Khi, 1 VbfT, 2 UhT, 3 EhiT, 4 EloT, 5 valsT, 6 Ughi, 7 Uglo
#define USZ ((size_t)16 * 2048 * 64)

typedef __attribute__((ext_vector_type(8))) short bf16x8;
typedef __attribute__((ext_vector_type(4))) float f32x4;
typedef __attribute__((ext_vector_type(8))) unsigned short us8;
typedef __attribute__((ext_vector_type(4))) unsigned short us4;

__device__ __forceinline__ unsigned short f2bf(float x) {
    union { float f; unsigned u; } v; v.f = x;
    unsigned r = v.u + 0x7fffu + ((v.u >> 16) & 1u);
    return (unsigned short)(r >> 16);
}
__device__ __forceinline__ float bf2f(unsigned short u) {
    union { unsigned u; float f; } v; v.u = ((unsigned)u) << 16; return v.f;
}
__device__ __forceinline__ void load16(const float* p, float* v) {
    const float4* q = (const float4*)p;
    float4 a = q[0], b = q[1], c = q[2], d = q[3];
    v[0]=a.x; v[1]=a.y; v[2]=a.z; v[3]=a.w;
    v[4]=b.x; v[5]=b.y; v[6]=b.z; v[7]=b.w;
    v[8]=c.x; v[9]=c.y; v[10]=c.z; v[11]=c.w;
    v[12]=d.x; v[13]=d.y; v[14]=d.z; v[15]=d.w;
}
__device__ __forceinline__ void wr_bf16x16(unsigned short* dst, const float* v) {
    us8 w0, w1;
#pragma unroll
    for (int i = 0; i < 8; i++) { w0[i] = f2bf(v[i]); w1[i] = f2bf(v[8 + i]); }
    *(us8*)dst = w0; *(us8*)(dst + 8) = w1;
}

// ================= prep: conversions / transposes + Ug (bf16 hi/lo) =================
__global__ __launch_bounds__(256) void prep(const float* __restrict__ U, const float* __restrict__ Sg,
                                            const float* __restrict__ Vagf, const float* __restrict__ vals,
                                            const float* __restrict__ Ksm, const float* __restrict__ Vsm,
                                            const float* __restrict__ gam,
                                            float* __restrict__ ws, unsigned short* __restrict__ usb,
                                            float* __restrict__ out) {
    int lt = blockIdx.x, p = blockIdx.y;
    int b = p >> 2, h = p & 3;
    int tid = threadIdx.x;
    int r = tid >> 2;
    int c0 = (tid & 3) * 16;
    __shared__ float T[64][68];
    unsigned short* Khi   = usb;
    unsigned short* VbfT  = usb + USZ;
    unsigned short* UhT   = usb + 2 * USZ;
    unsigned short* EhiT  = usb + 3 * USZ;
    unsigned short* EloT  = usb + 4 * USZ;
    unsigned short* valsT = usb + 5 * USZ;
    unsigned short* Ughi  = usb + 6 * USZ;
    unsigned short* Uglo  = usb + 7 * USZ;
    float* Spart = ws + OFF_SPART;

    const size_t gbase = ((size_t)(b * SEQ + lt * 64 + r) * NH + h) * D + c0;
    const size_t nbase = ((size_t)(p * SEQ + lt * 64 + r)) * 64 + c0;      // natural [p][l][d]
    const size_t tbase = ((size_t)p * 64 + r) * 2048 + lt * 64 + c0;      // transposed [p][d][l]
    float v[16], e[16];

    // ---- 1: U -> row softmax; write UhT (transposed) AND Ug=Uh*gf (natural hi/lo)
    load16(U + gbase, v);
    float mx = v[0];
#pragma unroll
    for (int k = 1; k < 16; k++) mx = fmaxf(mx, v[k]);
    mx = fmaxf(mx, __shfl_xor(mx, 1));
    mx = fmaxf(mx, __shfl_xor(mx, 2));
    float sm = 0.0f;
#pragma unroll
    for (int k = 0; k < 16; k++) { v[k] = __expf(v[k] - mx); sm += v[k]; }
    sm += __shfl_xor(sm, 1);
    sm += __shfl_xor(sm, 2);
    float inv = 1.0f / sm;
#pragma unroll
    for (int k = 0; k < 16; k++) { v[k] *= inv; T[r][c0 + k] = v[k]; }
    {
        float sg[16];
        load16(Sg + gbase, sg);
        float g0 = gam[0], g1 = gam[1], g2 = gam[2], g3 = gam[3];
        us8 h0, h1, l0, l1;
#pragma unroll
        for (int k = 0; k < 16; k++) {
            float sig = 1.0f / (1.0f + __expf(-sg[k]));
            float x1 = 2.0f * sig;
            float x2 = 1.875f * sig * x1 - 0.75f;
            float x3 = 1.8666666666666667f * sig * x2 - 0.8f * x1;
            float ug = v[k] * (g0 + g1 * x1 + g2 * x2 + g3 * x3);
            unsigned short hh = f2bf(ug);
            unsigned short ll = f2bf(ug - bf2f(hh));
            if (k < 8) { h0[k] = hh; l0[k] = ll; } else { h1[k - 8] = hh; l1[k - 8] = ll; }
        }
        *(us8*)(Ughi + nbase) = h0; *(us8*)(Ughi + nbase + 8) = h1;
        *(us8*)(Uglo + nbase) = l0; *(us8*)(Uglo + nbase + 8) = l1;
    }
    __syncthreads();
#pragma unroll
    for (int k = 0; k < 16; k++) e[k] = T[c0 + k][r];
    wr_bf16x16(UhT + tbase, e);
    __syncthreads();

    // ---- 2: E = exp(Vagf) -> EhiT/EloT + col sums
    load16(Vagf + gbase, v);
#pragma unroll
    for (int k = 0; k < 16; k++) T[r][c0 + k] = __expf(v[k]);
    __syncthreads();
    float ssum = 0.0f;
#pragma unroll
    for (int k = 0; k < 16; k++) { e[k] = T[c0 + k][r]; ssum += e[k]; }
    ssum += __shfl_xor(ssum, 1);
    ssum += __shfl_xor(ssum, 2);
    if ((tid & 3) == 0) Spart[(p * 32 + lt) * 64 + r] = ssum;
    {
        us8 h0, h1, l0, l1;
#pragma unroll
        for (int i = 0; i < 8; i++) {
            unsigned short hh = f2bf(e[i]);
            h0[i] = hh; l0[i] = f2bf(e[i] - bf2f(hh));
            unsigned short h2 = f2bf(e[8 + i]);
            h1[i] = h2; l1[i] = f2bf(e[8 + i] - bf2f(h2));
        }
        *(us8*)(EhiT + tbase) = h0; *(us8*)(EhiT + tbase + 8) = h1;
        *(us8*)(EloT + tbase) = l0; *(us8*)(EloT + tbase + 8) = l1;
    }
    __syncthreads();

    // ---- 3: vals -> valsT
    load16(vals + gbase, v);
#pragma unroll
    for (int k = 0; k < 16; k++) T[r][c0 + k] = v[k];
    __syncthreads();
#pragma unroll
    for (int k = 0; k < 16; k++) e[k] = T[c0 + k][r];
    wr_bf16x16(valsT + tbase, e);
    __syncthreads();

    // ---- 4: Vsm -> VbfT
    load16(Vsm + gbase, v);
#pragma unroll
    for (int k = 0; k < 16; k++) T[r][c0 + k] = v[k];
    __syncthreads();
#pragma unroll
    for (int k = 0; k < 16; k++) e[k] = T[c0 + k][r];
    wr_bf16x16(VbfT + tbase, e);

    // ---- 5: K -> Khi (row-major)
    load16(Ksm + gbase, v);
    wr_bf16x16(Khi + nbase, v);

    if (lt == 0 && p == 0 && tid < BB) out[LOSS_BASE + tid] = 0.0f;
}

// ================= mid: gram (blocks 0..127) + flash6 barrier-free (128..639) =================
#define PSTR 72

__global__ __launch_bounds__(256, 2) void mid(const unsigned short* __restrict__ usb,
                                              const float* __restrict__ Q,
                                              float* __restrict__ part, float* __restrict__ out) {
    __shared__ __align__(16) unsigned char smem[20480];
    const int bid = blockIdx.x;
    const int tid = threadIdx.x;
    const int w = tid >> 6, lane = tid & 63, lm = lane & 15, quad = lane >> 4;

    if (bid >= 128) {
        // ---------------- flash6: per-wave q-rows, K/V direct from global, NO barriers ----------------
        int fb = bid - 128;
        int qt = fb & 31, p = fb >> 5;
        int b = p >> 2, h = p & 3;
        const unsigned short* Khi  = usb;
        const unsigned short* VbfT = usb + USZ;
        unsigned short* Ph = (unsigned short*)smem + (size_t)w * 16 * PSTR;   // per-wave region

        // Q B-frags for this wave's 16 qrows: B[n=lm][k=quad*8+j], scale 1/8, hi/lo
        const int qrow = qt * 64 + w * 16 + lm;
        bf16x8 qhi[2], qlo[2];
        {
            const float* qp = Q + ((size_t)(b * SEQ + qrow) * NH + h) * D + quad * 8;
#pragma unroll
            for (int ks = 0; ks < 2; ks++) {
                float qq[8];
                float4 a0 = *(const float4*)(qp + ks * 32);
                float4 a1 = *(const float4*)(qp + ks * 32 + 4);
                qq[0]=a0.x; qq[1]=a0.y; qq[2]=a0.z; qq[3]=a0.w;
                qq[4]=a1.x; qq[5]=a1.y; qq[6]=a1.z; qq[7]=a1.w;
#pragma unroll
                for (int j = 0; j < 8; j++) {
                    float xs = qq[j] * 0.125f;
                    unsigned short hi = f2bf(xs);
                    qhi[ks][j] = (short)hi;
                    qlo[ks][j] = (short)f2bf(xs - bf2f(hi));
                }
            }
        }

        float rsum = 0.0f;
        f32x4 o[4];
#pragma unroll
        for (int t = 0; t < 4; t++) o[t] = (f32x4){0.f, 0.f, 0.f, 0.f};

        // A-frag base addresses
        // K[key=kt*64+t*16+lm][d=ks*32+quad*8..] ; V^T[d=dt*16+lm][key=kt*64+ks*32+quad*8..]
        const size_t kbase = ((size_t)p * SEQ + lm) * 64 + quad * 8;
        const size_t vbase = ((size_t)p * 64 + lm) * 2048 + quad * 8;

        bf16x8 kc[4][2], vc[4][2], kn[4][2], vn[4][2];
#pragma unroll
        for (int t = 0; t < 4; t++)
#pragma unroll
            for (int ks = 0; ks < 2; ks++) {
                kc[t][ks] = *(const bf16x8*)(Khi + kbase + (size_t)(t * 16) * 64 + ks * 32);
                vc[t][ks] = *(const bf16x8*)(VbfT + vbase + (size_t)(t * 16) * 2048 + ks * 32);
            }

        for (int kt = 0; kt < 32; ++kt) {
            if (kt < 31) {   // prefetch next tile
#pragma unroll
                for (int t = 0; t < 4; t++)
#pragma unroll
                    for (int ks = 0; ks < 2; ks++) {
                        kn[t][ks] = *(const bf16x8*)(Khi + kbase + (size_t)((kt + 1) * 64 + t * 16) * 64 + ks * 32);
                        vn[t][ks] = *(const bf16x8*)(VbfT + vbase + (size_t)(t * 16) * 2048 + (kt + 1) * 64 + ks * 32);
                    }
            }
            // S^T tile: m=key (t*16+quad*4+reg), n=qrow=lm. A=K, B=Q (2-pass Q hi/lo)
            f32x4 s[4];
#pragma unroll
            for (int t = 0; t < 4; t++) s[t] = (f32x4){0.f, 0.f, 0.f, 0.f};
#pragma unroll
            for (int t = 0; t < 4; t++)
#pragma unroll
                for (int ks = 0; ks < 2; ks++) {
                    s[t] = __builtin_amdgcn_mfma_f32_16x16x32_bf16(kc[t][ks], qhi[ks], s[t], 0, 0, 0);
                    s[t] = __builtin_amdgcn_mfma_f32_16x16x32_bf16(kc[t][ks], qlo[ks], s[t], 0, 0, 0);
                }
            // p = exp(s) (no max shift needed: |s|<~8, ratio-invariant), pack, per-wave LDS
#pragma unroll
            for (int t = 0; t < 4; t++) {
                float e0 = __expf(s[t][0]);
                float e1 = __expf(s[t][1]);
                float e2 = __expf(s[t][2]);
                float e3 = __expf(s[t][3]);
                rsum += (e0 + e1) + (e2 + e3);
                union { __hip_bfloat162 h2[2]; us4 u4; } pk;
                pk.h2[0] = __float22bfloat162_rn(make_float2(e0, e1));
                pk.h2[1] = __float22bfloat162_rn(make_float2(e2, e3));
                *(us4*)&Ph[lm * PSTR + t * 16 + quad * 4] = pk.u4;
            }
            // same-wave write->read: lgkmcnt ordering, no barrier
            bf16x8 pf0 = *(const bf16x8*)&Ph[lm * PSTR + quad * 8];
            bf16x8 pf1 = *(const bf16x8*)&Ph[lm * PSTR + 32 + quad * 8];
            // O^T[m=d][n=qrow] += V^T · P
#pragma unroll
            for (int dt = 0; dt < 4; dt++) {
                o[dt] = __builtin_amdgcn_mfma_f32_16x16x32_bf16(vc[dt][0], pf0, o[dt], 0, 0, 0);
                o[dt] = __builtin_amdgcn_mfma_f32_16x16x32_bf16(vc[dt][1], pf1, o[dt], 0, 0, 0);
            }
#pragma unroll
            for (int t = 0; t < 4; t++)
#pragma unroll
                for (int ks = 0; ks < 2; ks++) { kc[t][ks] = kn[t][ks]; vc[t][ks] = vn[t][ks]; }
        }

        // epilogue: full denominator = reduce over quads; direct final store
        rsum += __shfl_xor(rsum, 16);
        rsum += __shfl_xor(rsum, 32);
        float invd = 1.0f / rsum;
        float* op = out + ((size_t)(b * SEQ + qrow) * HOUT + 4 + h) * D + quad * 4;
#pragma unroll
        for (int dt = 0; dt < 4; dt++)
            *(f32x4*)(op + dt * 16) = o[dt] * invd;
    } else {
        // ---------------- gram: MFMA split-8 partials ----------------
        int split = bid >> 4, p = bid & 15;
        const unsigned short* UhT   = usb + 2 * USZ;
        const unsigned short* EhiT  = usb + 3 * USZ;
        const unsigned short* EloT  = usb + 4 * USZ;
        const unsigned short* valsT = usb + 5 * USZ;
        unsigned short* Ut = (unsigned short*)smem;            // 64*40 each
        unsigned short* Eh = Ut + 64 * 40;
        unsigned short* El = Eh + 64 * 40;
        unsigned short* Vt = El + 64 * 40;
        f32x4 su[4], sv[4], kv[4];
#pragma unroll
        for (int i = 0; i < 4; i++) { su[i] = (f32x4){0,0,0,0}; sv[i] = (f32x4){0,0,0,0}; kv[i] = (f32x4){0,0,0,0}; }
        int srow = tid >> 2;
        int sseg = (tid & 3) * 8;

        for (int step = 0; step < 8; ++step) {
            int l0 = split * 256 + step * 32;
            __syncthreads();
            size_t gb = ((size_t)p * 64 + srow) * 2048 + l0 + sseg;
            *(us8*)&Ut[srow * 40 + sseg] = *(const us8*)(UhT + gb);
            *(us8*)&Eh[srow * 40 + sseg] = *(const us8*)(EhiT + gb);
            *(us8*)&El[srow * 40 + sseg] = *(const us8*)(EloT + gb);
            *(us8*)&Vt[srow * 40 + sseg] = *(const us8*)(valsT + gb);
            __syncthreads();
            int ao = (w * 16 + lm) * 40 + quad * 8;
            bf16x8 au  = *(const bf16x8*)&Ut[ao];
            bf16x8 aeh = *(const bf16x8*)&Eh[ao];
            bf16x8 ael = *(const bf16x8*)&El[ao];
#pragma unroll
            for (int nt = 0; nt < 4; nt++) {
                int bo = (nt * 16 + lm) * 40 + quad * 8;
                bf16x8 bu  = *(const bf16x8*)&Ut[bo];
                bf16x8 beh = *(const bf16x8*)&Eh[bo];
                bf16x8 bv  = *(const bf16x8*)&Vt[bo];
                su[nt] = __builtin_amdgcn_mfma_f32_16x16x32_bf16(au,  bu,  su[nt], 0, 0, 0);
                sv[nt] = __builtin_amdgcn_mfma_f32_16x16x32_bf16(aeh, beh, sv[nt], 0, 0, 0);
                kv[nt] = __builtin_amdgcn_mfma_f32_16x16x32_bf16(aeh, bv,  kv[nt], 0, 0, 0);
                kv[nt] = __builtin_amdgcn_mfma_f32_16x16x32_bf16(ael, bv,  kv[nt], 0, 0, 0);
            }
        }
        float* dst = part + (size_t)(split * 16 + p) * 3 * 4096;
#pragma unroll
        for (int nt = 0; nt < 4; nt++)
#pragma unroll
            for (int reg = 0; reg < 4; reg++) {
                int off = (w * 16 + quad * 4 + reg) * 64 + nt * 16 + lm;
                dst[off] = su[nt][reg];
                dst[4096 + off] = sv[nt][reg];
                dst[8192 + off] = kv[nt][reg];
            }
    }
}

// ================= post: agf MFMA (0..511) + ortho (512..527) =================
__global__ __launch_bounds__(256) void post(const float* __restrict__ part, const float* __restrict__ Spart,
                                            const unsigned short* __restrict__ usb, float* __restrict__ out) {
    const int bid = blockIdx.x;
    const int tid = threadIdx.x;
    const int w = tid >> 6, lane = tid & 63, lm = lane & 15, quad = lane >> 4;
    int p = (bid < 512) ? (bid >> 5) : (bid - 512);
    __shared__ float cis[64];
    __shared__ float red[4][64];
    __shared__ __align__(16) unsigned short KVh[64 * PSTR];
    __shared__ __align__(16) unsigned short KVl[64 * PSTR];
    {
        int d = tid & 63, grp = tid >> 6;
        float s = 0.0f;
#pragma unroll
        for (int i = 0; i < 8; i++) s += Spart[(p * 32 + grp * 8 + i) * 64 + d];
        red[grp][d] = s;
        __syncthreads();
        if (tid < 64) cis[tid] = 1.0f / (red[0][tid] + red[1][tid] + red[2][tid] + red[3][tid]);
        __syncthreads();
    }
    if (bid >= 512) {
        // ortho loss for pair p
        float s = 0.0f;
        for (int idx = tid; idx < 8192; idx += 256) {
            int g = idx >> 12, i = idx & 4095;
            float v = 0.0f;
#pragma unroll
            for (int sp = 0; sp < 8; sp++) v += part[((size_t)(sp * 16 + p) * 3 + g) * 4096 + i];
            if (g) v *= cis[i >> 6] * cis[i & 63];
            float dg = ((i >> 6) == (i & 63)) ? 1.0f : 0.0f;
            s += fabsf(v - dg);
        }
#pragma unroll
        for (int o = 32; o > 0; o >>= 1) s += __shfl_xor(s, o);
        if ((tid & 63) == 0) red[0][(tid >> 6) * 2] = s;   // reuse red
        __syncthreads();
        if (tid == 0)
            atomicAdd(&out[LOSS_BASE + (p >> 2)],
                      (red[0][0] + red[0][2] + red[0][4] + red[0][6]) * (1.0f / 16384.0f));
        return;
    }
    // agf: out_tile[l=lt*64+.., e] = Ug @ KV  (3-pass bf16 MFMA)
    int lt = bid & 31;
    int b = p >> 2, h = p & 3;
    const unsigned short* Ughi = usb + 6 * USZ;
    const unsigned short* Uglo = usb + 7 * USZ;
    // stage KV^T (e-major) hi/lo, scaled by ci[d]
    for (int idx = tid; idx < 4096; idx += 256) {
        int d = idx >> 6, e = idx & 63;
        float v = 0.0f;
#pragma unroll
        for (int sp = 0; sp < 8; sp++) v += part[((size_t)(sp * 16 + p) * 3 + 2) * 4096 + idx];
        v *= cis[d];
        unsigned short hh = f2bf(v);
        KVh[e * PSTR + d] = hh;
        KVl[e * PSTR + d] = f2bf(v - bf2f(hh));
    }
    __syncthreads();
    // A = Ug rows (wave's 16 l-rows), B = KV^T from LDS
    size_t ub = ((size_t)(p * SEQ + lt * 64 + w * 16 + lm)) * 64 + quad * 8;
    bf16x8 ah[2], al[2];
#pragma unroll
    for (int ks = 0; ks < 2; ks++) {
        ah[ks] = *(const bf16x8*)(Ughi + ub + ks * 32);
        al[ks] = *(const bf16x8*)(Uglo + ub + ks * 32);
    }
    f32x4 acc[4];
#pragma unroll
    for (int nt = 0; nt < 4; nt++) acc[nt] = (f32x4){0.f, 0.f, 0.f, 0.f};
#pragma unroll
    for (int nt = 0; nt < 4; nt++)
#pragma unroll
        for (int ks = 0; ks < 2; ks++) {
            bf16x8 bh = *(const bf16x8*)&KVh[(nt * 16 + lm) * PSTR + ks * 32 + quad * 8];
            bf16x8 bl = *(const bf16x8*)&KVl[(nt * 16 + lm) * PSTR + ks * 32 + quad * 8];
            acc[nt] = __builtin_amdgcn_mfma_f32_16x16x32_bf16(ah[ks], bh, acc[nt], 0, 0, 0);
            acc[nt] = __builtin_amdgcn_mfma_f32_16x16x32_bf16(al[ks], bh, acc[nt], 0, 0, 0);
            acc[nt] = __builtin_amdgcn_mfma_f32_16x16x32_bf16(ah[ks], bl, acc[nt], 0, 0, 0);
        }
    // C: row = l (quad*4+reg within wave tile), col = e (nt*16+lm)
#pragma unroll
    for (int nt = 0; nt < 4; nt++)
#pragma unroll
        for (int reg = 0; reg < 4; reg++)
            out[((size_t)(b * SEQ + lt * 64 + w * 16 + quad * 4 + reg) * HOUT + h) * D + nt * 16 + lm] =
                acc[nt][reg];
}

extern "C" void kernel_launch(void* const* d_in, const int* in_sizes, int n_in,
                              void* d_out, int out_size, void* d_ws, size_t ws_size,
                              hipStream_t stream) {
    (void)in_sizes; (void)n_in; (void)out_size; (void)ws_size;
    const float* U    = (const float*)d_in[0];
    const float* Sg   = (const float*)d_in[1];
    const float* V    = (const float*)d_in[2];
    const float* vals = (const float*)d_in[3];
    const float* Qs   = (const float*)d_in[4];
    const float* Ks   = (const float*)d_in[5];
    const float* Vv   = (const float*)d_in[6];
    const float* gam  = (const float*)d_in[7];
    float* out = (float*)d_out;

    float* ws = (float*)d_ws;
    float* part  = ws + OFF_PART;
    float* Spart = ws + OFF_SPART;
    unsigned short* usb = (unsigned short*)(ws + OFF_US);

    prep<<<dim3(32, 16), 256, 0, stream>>>(U, Sg, V, vals, Ks, Vv, gam, ws, usb, out);
    mid<<<640, 256, 0, stream>>>(usb, Qs, part, out);
    post<<<528, 256, 0, stream>>>(part, Spart, usb, out);
}

// Round 10
// 166.967 us; speedup vs baseline: 1.4824x; 1.4824x over previous
//
#include <hip/hip_runtime.h>
#include <hip/hip_bf16.h>

#define BB 4
#define SEQ 2048
#define NH 4
#define D 64
#define NPAIR 16
#define HOUT 8
#define LOSS_BASE ((size_t)BB * SEQ * HOUT * D)

// ---- ws layout ----
// f32: part[4][16][3][4096] | Spart[16][32][64] | lpart[2][16][2048]
// ushort: usb: 0 Khi, 1 VbfT, 2 UhT, 3 EhiT, 4 valsT, 5 Ughi, 6 Uglo  (each 16*2048*64)
// ushort: OpartUS[2][16][2048][64]
#define N_PART   (4 * 16 * 3 * 4096)
#define OFF_SPART N_PART
#define N_SPART  (16 * 32 * 64)
#define OFF_LPART (OFF_SPART + N_SPART)
#define N_LPART  (2 * 16 * 2048)
#define OFF_F32_END (OFF_LPART + N_LPART)
#define USZ ((size_t)16 * 2048 * 64)

typedef __attribute__((ext_vector_type(8))) short bf16x8;
typedef __attribute__((ext_vector_type(4))) float f32x4;
typedef __attribute__((ext_vector_type(8))) unsigned short us8;
typedef __attribute__((ext_vector_type(4))) unsigned short us4;

__device__ __forceinline__ unsigned short f2bf(float x) {
    union { float f; unsigned u; } v; v.f = x;
    unsigned r = v.u + 0x7fffu + ((v.u >> 16) & 1u);
    return (unsigned short)(r >> 16);
}
__device__ __forceinline__ float bf2f(unsigned short u) {
    union { unsigned u; float f; } v; v.u = ((unsigned)u) << 16; return v.f;
}
__device__ __forceinline__ void load16(const float* p, float* v) {
    const float4* q = (const float4*)p;
    float4 a = q[0], b = q[1], c = q[2], d = q[3];
    v[0]=a.x; v[1]=a.y; v[2]=a.z; v[3]=a.w;
    v[4]=b.x; v[5]=b.y; v[6]=b.z; v[7]=b.w;
    v[8]=c.x; v[9]=c.y; v[10]=c.z; v[11]=c.w;
    v[12]=d.x; v[13]=d.y; v[14]=d.z; v[15]=d.w;
}
__device__ __forceinline__ void wr_bf16x16(unsigned short* dst, const float* v) {
    us8 w0, w1;
#pragma unroll
    for (int i = 0; i < 8; i++) { w0[i] = f2bf(v[i]); w1[i] = f2bf(v[8 + i]); }
    *(us8*)dst = w0; *(us8*)(dst + 8) = w1;
}

// ================= prep: stage-parallel conversions (z = stage) =================
__global__ __launch_bounds__(256) void prep(const float* __restrict__ U, const float* __restrict__ Sg,
                                            const float* __restrict__ Vagf, const float* __restrict__ vals,
                                            const float* __restrict__ Ksm, const float* __restrict__ Vsm,
                                            const float* __restrict__ gam,
                                            float* __restrict__ ws, unsigned short* __restrict__ usb,
                                            float* __restrict__ out) {
    int lt = blockIdx.x, p = blockIdx.y, stage = blockIdx.z;
    int b = p >> 2, h = p & 3;
    int tid = threadIdx.x;
    int r = tid >> 2;
    int c0 = (tid & 3) * 16;
    __shared__ float T[64][68];
    unsigned short* Khi   = usb;
    unsigned short* VbfT  = usb + USZ;
    unsigned short* UhT   = usb + 2 * USZ;
    unsigned short* EhiT  = usb + 3 * USZ;
    unsigned short* valsT = usb + 4 * USZ;
    unsigned short* Ughi  = usb + 5 * USZ;
    unsigned short* Uglo  = usb + 6 * USZ;
    float* Spart = ws + OFF_SPART;

    const size_t gbase = ((size_t)(b * SEQ + lt * 64 + r) * NH + h) * D + c0;
    const size_t nbase = ((size_t)(p * SEQ + lt * 64 + r)) * 64 + c0;      // [p][l][d]
    const size_t tbase = ((size_t)p * 64 + r) * 2048 + lt * 64 + c0;      // [p][d][l]
    float v[16], e[16];

    if (stage == 0) {
        // U -> row softmax -> Ug (natural hi/lo) + UhT (transposed bf16)
        load16(U + gbase, v);
        float mx = v[0];
#pragma unroll
        for (int k = 1; k < 16; k++) mx = fmaxf(mx, v[k]);
        mx = fmaxf(mx, __shfl_xor(mx, 1));
        mx = fmaxf(mx, __shfl_xor(mx, 2));
        float sm = 0.0f;
#pragma unroll
        for (int k = 0; k < 16; k++) { v[k] = __expf(v[k] - mx); sm += v[k]; }
        sm += __shfl_xor(sm, 1);
        sm += __shfl_xor(sm, 2);
        float inv = 1.0f / sm;
#pragma unroll
        for (int k = 0; k < 16; k++) { v[k] *= inv; T[r][c0 + k] = v[k]; }
        float sg[16];
        load16(Sg + gbase, sg);
        float g0 = gam[0], g1 = gam[1], g2 = gam[2], g3 = gam[3];
        us8 h0, h1, l0, l1;
#pragma unroll
        for (int k = 0; k < 16; k++) {
            float sig = 1.0f / (1.0f + __expf(-sg[k]));
            float x1 = 2.0f * sig;
            float x2 = 1.875f * sig * x1 - 0.75f;
            float x3 = 1.8666666666666667f * sig * x2 - 0.8f * x1;
            float ug = v[k] * (g0 + g1 * x1 + g2 * x2 + g3 * x3);
            unsigned short hh = f2bf(ug);
            unsigned short ll = f2bf(ug - bf2f(hh));
            if (k < 8) { h0[k] = hh; l0[k] = ll; } else { h1[k - 8] = hh; l1[k - 8] = ll; }
        }
        *(us8*)(Ughi + nbase) = h0; *(us8*)(Ughi + nbase + 8) = h1;
        *(us8*)(Uglo + nbase) = l0; *(us8*)(Uglo + nbase + 8) = l1;
        __syncthreads();
#pragma unroll
        for (int k = 0; k < 16; k++) e[k] = T[c0 + k][r];
        wr_bf16x16(UhT + tbase, e);
    } else if (stage == 1) {
        // E = exp(Vagf) -> EhiT + column sums
        load16(Vagf + gbase, v);
#pragma unroll
        for (int k = 0; k < 16; k++) T[r][c0 + k] = __expf(v[k]);
        __syncthreads();
        float ssum = 0.0f;
#pragma unroll
        for (int k = 0; k < 16; k++) { e[k] = T[c0 + k][r]; ssum += e[k]; }
        ssum += __shfl_xor(ssum, 1);
        ssum += __shfl_xor(ssum, 2);
        if ((tid & 3) == 0) Spart[(p * 32 + lt) * 64 + r] = ssum;
        wr_bf16x16(EhiT + tbase, e);
    } else if (stage == 2) {
        load16(vals + gbase, v);
#pragma unroll
        for (int k = 0; k < 16; k++) T[r][c0 + k] = v[k];
        __syncthreads();
#pragma unroll
        for (int k = 0; k < 16; k++) e[k] = T[c0 + k][r];
        wr_bf16x16(valsT + tbase, e);
    } else if (stage == 3) {
        load16(Vsm + gbase, v);
#pragma unroll
        for (int k = 0; k < 16; k++) T[r][c0 + k] = v[k];
        __syncthreads();
#pragma unroll
        for (int k = 0; k < 16; k++) e[k] = T[c0 + k][r];
        wr_bf16x16(VbfT + tbase, e);
    } else {
        load16(Ksm + gbase, v);
        wr_bf16x16(Khi + nbase, v);
        if (lt == 0 && p == 0 && tid < BB) out[LOSS_BASE + tid] = 0.0f;
    }
}

// ================= mid: gram (0..63) + flash7 (64..575) =================
#define PSTR 72

__global__ __launch_bounds__(256, 2) void mid(const unsigned short* __restrict__ usb,
                                              const float* __restrict__ Q,
                                              float* __restrict__ part,
                                              unsigned short* __restrict__ OpartUS,
                                              float* __restrict__ lpart) {
    __shared__ __align__(16) unsigned char smem[36864];
    const int bid = blockIdx.x;
    const int tid = threadIdx.x;
    const int w = tid >> 6, lane = tid & 63, lm = lane & 15, quad = lane >> 4;

    if (bid >= 64) {
        // ---------------- flash7: 128 qrows/block, LDS K/V, reg-cached A-frags, split-K x2 ----------------
        int fb = bid - 64;
        int qt2 = fb & 15, p = (fb >> 4) & 15, half = fb >> 8;
        int b = p >> 2, h = p & 3;
        const unsigned short* Khi  = usb;
        const unsigned short* VbfT = usb + USZ;
        unsigned short* Kl = (unsigned short*)smem;                        // [64][PSTR]
        unsigned short* Vl = Kl + 64 * PSTR;                               // [64][PSTR] (rows=d)
        unsigned short* Ph = Vl + 64 * PSTR;                               // [4w][2q][16][PSTR]
        const int srow = tid >> 2, sseg = (tid & 3) * 16;

        // Q B-frags for 2 q-subs: B[n=lm][k=quad*8+j], scale 1/8, hi/lo
        bf16x8 qhi[2][2], qlo[2][2];
#pragma unroll
        for (int q = 0; q < 2; q++) {
            int row = qt2 * 128 + q * 64 + w * 16 + lm;
            const float* qp = Q + ((size_t)(b * SEQ + row) * NH + h) * D + quad * 8;
#pragma unroll
            for (int ks = 0; ks < 2; ks++) {
                float qq[8];
                float4 a0 = *(const float4*)(qp + ks * 32);
                float4 a1 = *(const float4*)(qp + ks * 32 + 4);
                qq[0]=a0.x; qq[1]=a0.y; qq[2]=a0.z; qq[3]=a0.w;
                qq[4]=a1.x; qq[5]=a1.y; qq[6]=a1.z; qq[7]=a1.w;
#pragma unroll
                for (int j = 0; j < 8; j++) {
                    float xs = qq[j] * 0.125f;
                    unsigned short hi = f2bf(xs);
                    qhi[q][ks][j] = (short)hi;
                    qlo[q][ks][j] = (short)f2bf(xs - bf2f(hi));
                }
            }
        }

        float rsum[2] = {0.f, 0.f};
        f32x4 o[2][4];
#pragma unroll
        for (int q = 0; q < 2; q++)
#pragma unroll
            for (int t = 0; t < 4; t++) o[q][t] = (f32x4){0.f, 0.f, 0.f, 0.f};

        for (int kt = 0; kt < 16; ++kt) {
            __syncthreads();
            {   // stage K [key][d] and V^T [d][key]
                size_t kb = ((size_t)(p * SEQ + half * 1024 + kt * 64 + srow)) * 64 + sseg;
                us8 k0 = *(const us8*)(Khi + kb);
                us8 k1 = *(const us8*)(Khi + kb + 8);
                size_t vb = ((size_t)p * 64 + srow) * 2048 + half * 1024 + kt * 64 + sseg;
                us8 v0 = *(const us8*)(VbfT + vb);
                us8 v1 = *(const us8*)(VbfT + vb + 8);
                *(us8*)&Kl[srow * PSTR + sseg] = k0; *(us8*)&Kl[srow * PSTR + sseg + 8] = k1;
                *(us8*)&Vl[srow * PSTR + sseg] = v0; *(us8*)&Vl[srow * PSTR + sseg + 8] = v1;
            }
            __syncthreads();

            // A-frags once per tile, reused by both q-subs
            bf16x8 kfr[4][2], vfr[4][2];
#pragma unroll
            for (int t = 0; t < 4; t++)
#pragma unroll
                for (int ks = 0; ks < 2; ks++) {
                    kfr[t][ks] = *(const bf16x8*)&Kl[(t * 16 + lm) * PSTR + ks * 32 + quad * 8];
                    vfr[t][ks] = *(const bf16x8*)&Vl[(t * 16 + lm) * PSTR + ks * 32 + quad * 8];
                }

#pragma unroll
            for (int q = 0; q < 2; q++) {
                unsigned short* Phq = Ph + (size_t)(w * 2 + q) * 16 * PSTR;
                // S^T: m=key, n=qrow. 2-pass Q hi/lo
                f32x4 s[4];
#pragma unroll
                for (int t = 0; t < 4; t++) s[t] = (f32x4){0.f, 0.f, 0.f, 0.f};
#pragma unroll
                for (int t = 0; t < 4; t++)
#pragma unroll
                    for (int ks = 0; ks < 2; ks++) {
                        s[t] = __builtin_amdgcn_mfma_f32_16x16x32_bf16(kfr[t][ks], qhi[q][ks], s[t], 0, 0, 0);
                        s[t] = __builtin_amdgcn_mfma_f32_16x16x32_bf16(kfr[t][ks], qlo[q][ks], s[t], 0, 0, 0);
                    }
                // p = exp(s), pack, per-wave LDS
#pragma unroll
                for (int t = 0; t < 4; t++) {
                    float e0 = __expf(s[t][0]);
                    float e1 = __expf(s[t][1]);
                    float e2 = __expf(s[t][2]);
                    float e3 = __expf(s[t][3]);
                    rsum[q] += (e0 + e1) + (e2 + e3);
                    us4 pk;
                    pk[0] = f2bf(e0); pk[1] = f2bf(e1); pk[2] = f2bf(e2); pk[3] = f2bf(e3);
                    *(us4*)&Phq[lm * PSTR + t * 16 + quad * 4] = pk;
                }
                // same-wave write->read ordering via lgkmcnt
                bf16x8 pf0 = *(const bf16x8*)&Phq[lm * PSTR + quad * 8];
                bf16x8 pf1 = *(const bf16x8*)&Phq[lm * PSTR + 32 + quad * 8];
#pragma unroll
                for (int dt = 0; dt < 4; dt++) {
                    o[q][dt] = __builtin_amdgcn_mfma_f32_16x16x32_bf16(vfr[dt][0], pf0, o[q][dt], 0, 0, 0);
                    o[q][dt] = __builtin_amdgcn_mfma_f32_16x16x32_bf16(vfr[dt][1], pf1, o[q][dt], 0, 0, 0);
                }
            }
        }

        // epilogue: bf16 partials + per-qrow denominator partial
#pragma unroll
        for (int q = 0; q < 2; q++) {
            float rs = rsum[q];
            rs += __shfl_xor(rs, 16);
            rs += __shfl_xor(rs, 32);
            int qrow = qt2 * 128 + q * 64 + w * 16 + lm;
            size_t ob = ((size_t)(half * 16 + p) * SEQ + qrow) * 64;
#pragma unroll
            for (int dt = 0; dt < 4; dt++) {
                us4 pk;
#pragma unroll
                for (int r = 0; r < 4; r++) pk[r] = f2bf(o[q][dt][r]);
                *(us4*)(OpartUS + ob + dt * 16 + quad * 4) = pk;
            }
            if (quad == 0) lpart[(size_t)(half * 16 + p) * SEQ + qrow] = rs;
        }
    } else {
        // ---------------- gram: MFMA split-4 partials ----------------
        int split = bid >> 4, p = bid & 15;
        const unsigned short* UhT   = usb + 2 * USZ;
        const unsigned short* EhiT  = usb + 3 * USZ;
        const unsigned short* valsT = usb + 4 * USZ;
        unsigned short* Ut = (unsigned short*)smem;            // 64*40 each
        unsigned short* Eh = Ut + 64 * 40;
        unsigned short* Vt = Eh + 64 * 40;
        f32x4 su[4], sv[4], kv[4];
#pragma unroll
        for (int i = 0; i < 4; i++) { su[i] = (f32x4){0,0,0,0}; sv[i] = (f32x4){0,0,0,0}; kv[i] = (f32x4){0,0,0,0}; }
        int srow = tid >> 2;
        int sseg = (tid & 3) * 8;

        for (int step = 0; step < 16; ++step) {
            int l0 = split * 512 + step * 32;
            __syncthreads();
            size_t gb = ((size_t)p * 64 + srow) * 2048 + l0 + sseg;
            *(us8*)&Ut[srow * 40 + sseg] = *(const us8*)(UhT + gb);
            *(us8*)&Eh[srow * 40 + sseg] = *(const us8*)(EhiT + gb);
            *(us8*)&Vt[srow * 40 + sseg] = *(const us8*)(valsT + gb);
            __syncthreads();
            int ao = (w * 16 + lm) * 40 + quad * 8;
            bf16x8 au  = *(const bf16x8*)&Ut[ao];
            bf16x8 aeh = *(const bf16x8*)&Eh[ao];
#pragma unroll
            for (int nt = 0; nt < 4; nt++) {
                int bo = (nt * 16 + lm) * 40 + quad * 8;
                bf16x8 bu  = *(const bf16x8*)&Ut[bo];
                bf16x8 beh = *(const bf16x8*)&Eh[bo];
                bf16x8 bv  = *(const bf16x8*)&Vt[bo];
                su[nt] = __builtin_amdgcn_mfma_f32_16x16x32_bf16(au,  bu,  su[nt], 0, 0, 0);
                sv[nt] = __builtin_amdgcn_mfma_f32_16x16x32_bf16(aeh, beh, sv[nt], 0, 0, 0);
                kv[nt] = __builtin_amdgcn_mfma_f32_16x16x32_bf16(aeh, bv,  kv[nt], 0, 0, 0);
            }
        }
        float* dst = part + (size_t)(split * 16 + p) * 3 * 4096;
#pragma unroll
        for (int nt = 0; nt < 4; nt++)
#pragma unroll
            for (int reg = 0; reg < 4; reg++) {
                int off = (w * 16 + quad * 4 + reg) * 64 + nt * 16 + lm;
                dst[off] = su[nt][reg];
                dst[4096 + off] = sv[nt][reg];
                dst[8192 + off] = kv[nt][reg];
            }
    }
}

// ================= post: smerge (0..2047) + agf (2048..2559) + ortho (2560..2575) =================
__global__ __launch_bounds__(256) void post(const float* __restrict__ part, const float* __restrict__ Spart,
                                            const unsigned short* __restrict__ usb,
                                            const unsigned short* __restrict__ OpartUS,
                                            const float* __restrict__ lpart, float* __restrict__ out) {
    const int bid = blockIdx.x;
    const int tid = threadIdx.x;
    if (bid < 2048) {
        int idx = bid * 256 + tid;            // [p][l][16 dq]
        int p = idx >> 15;
        int rem = idx & 32767;
        int l = rem >> 4, dq = rem & 15;
        int b = p >> 2, h = p & 3;
        us4 a = *(const us4*)(OpartUS + ((size_t)p * SEQ + l) * 64 + dq * 4);
        us4 c = *(const us4*)(OpartUS + ((size_t)(16 + p) * SEQ + l) * 64 + dq * 4);
        float inv = 1.0f / (lpart[(size_t)p * SEQ + l] + lpart[(size_t)(16 + p) * SEQ + l]);
        f32x4 res;
#pragma unroll
        for (int r = 0; r < 4; r++) res[r] = (bf2f(a[r]) + bf2f(c[r])) * inv;
        *(f32x4*)(out + ((size_t)(b * SEQ + l) * HOUT + 4 + h) * D + dq * 4) = res;
        return;
    }
    const int w = tid >> 6, lane = tid & 63, lm = lane & 15, quad = lane >> 4;
    int j = bid - 2048;
    int p = (j < 512) ? (j >> 5) : (j - 512);
    __shared__ float cis[64];
    __shared__ float red[4][64];
    __shared__ __align__(16) unsigned short KVh[64 * PSTR];
    __shared__ __align__(16) unsigned short KVl[64 * PSTR];
    {
        int d = tid & 63, grp = tid >> 6;
        float s = 0.0f;
#pragma unroll
        for (int i = 0; i < 8; i++) s += Spart[(p * 32 + grp * 8 + i) * 64 + d];
        red[grp][d] = s;
        __syncthreads();
        if (tid < 64) cis[tid] = 1.0f / (red[0][tid] + red[1][tid] + red[2][tid] + red[3][tid]);
        __syncthreads();
    }
    if (j >= 512) {
        // ortho loss for pair p
        float s = 0.0f;
        for (int idx = tid; idx < 8192; idx += 256) {
            int g = idx >> 12, i = idx & 4095;
            float v = 0.0f;
#pragma unroll
            for (int sp = 0; sp < 4; sp++) v += part[((size_t)(sp * 16 + p) * 3 + g) * 4096 + i];
            if (g) v *= cis[i >> 6] * cis[i & 63];
            float dg = ((i >> 6) == (i & 63)) ? 1.0f : 0.0f;
            s += fabsf(v - dg);
        }
#pragma unroll
        for (int o = 32; o > 0; o >>= 1) s += __shfl_xor(s, o);
        if ((tid & 63) == 0) red[0][(tid >> 6) * 2] = s;
        __syncthreads();
        if (tid == 0)
            atomicAdd(&out[LOSS_BASE + (p >> 2)],
                      (red[0][0] + red[0][2] + red[0][4] + red[0][6]) * (1.0f / 16384.0f));
        return;
    }
    // agf: out = Ug @ KV (3-pass bf16 MFMA)
    int lt = j & 31;
    int b = p >> 2, h = p & 3;
    const unsigned short* Ughi = usb + 5 * USZ;
    const unsigned short* Uglo = usb + 6 * USZ;
    for (int idx = tid; idx < 4096; idx += 256) {
        int d = idx >> 6, e = idx & 63;
        float v = 0.0f;
#pragma unroll
        for (int sp = 0; sp < 4; sp++) v += part[((size_t)(sp * 16 + p) * 3 + 2) * 4096 + idx];
        v *= cis[d];
        unsigned short hh = f2bf(v);
        KVh[e * PSTR + d] = hh;
        KVl[e * PSTR + d] = f2bf(v - bf2f(hh));
    }
    __syncthreads();
    size_t ub = ((size_t)(p * SEQ + lt * 64 + w * 16 + lm)) * 64 + quad * 8;
    bf16x8 ah[2], al[2];
#pragma unroll
    for (int ks = 0; ks < 2; ks++) {
        ah[ks] = *(const bf16x8*)(Ughi + ub + ks * 32);
        al[ks] = *(const bf16x8*)(Uglo + ub + ks * 32);
    }
    f32x4 acc[4];
#pragma unroll
    for (int nt = 0; nt < 4; nt++) acc[nt] = (f32x4){0.f, 0.f, 0.f, 0.f};
#pragma unroll
    for (int nt = 0; nt < 4; nt++)
#pragma unroll
        for (int ks = 0; ks < 2; ks++) {
            bf16x8 bh = *(const bf16x8*)&KVh[(nt * 16 + lm) * PSTR + ks * 32 + quad * 8];
            bf16x8 bl = *(const bf16x8*)&KVl[(nt * 16 + lm) * PSTR + ks * 32 + quad * 8];
            acc[nt] = __builtin_amdgcn_mfma_f32_16x16x32_bf16(ah[ks], bh, acc[nt], 0, 0, 0);
            acc[nt] = __builtin_amdgcn_mfma_f32_16x16x32_bf16(al[ks], bh, acc[nt], 0, 0, 0);
            acc[nt] = __builtin_amdgcn_mfma_f32_16x16x32_bf16(ah[ks], bl, acc[nt], 0, 0, 0);
        }
#pragma unroll
    for (int nt = 0; nt < 4; nt++)
#pragma unroll
        for (int reg = 0; reg < 4; reg++)
            out[((size_t)(b * SEQ + lt * 64 + w * 16 + quad * 4 + reg) * HOUT + h) * D + nt * 16 + lm] =
                acc[nt][reg];
}

extern "C" void kernel_launch(void* const* d_in, const int* in_sizes, int n_in,
                              void* d_out, int out_size, void* d_ws, size_t ws_size,
                              hipStream_t stream) {
    (void)in_sizes; (void)n_in; (void)out_size; (void)ws_size;
    const float* U    = (const float*)d_in[0];
    const float* Sg   = (const float*)d_in[1];
    const float* V    = (const float*)d_in[2];
    const float* vals = (const float*)d_in[3];
    const float* Qs   = (const float*)d_in[4];
    const float* Ks   = (const float*)d_in[5];
    const float* Vv   = (const float*)d_in[6];
    const float* gam  = (const float*)d_in[7];
    float* out = (float*)d_out;

    float* ws = (float*)d_ws;
    float* part  = ws;
    float* Spart = ws + OFF_SPART;
    float* lpart = ws + OFF_LPART;
    unsigned short* usb = (unsigned short*)(ws + OFF_F32_END);
    unsigned short* OpartUS = usb + 7 * USZ;

    prep<<<dim3(32, 16, 5), 256, 0, stream>>>(U, Sg, V, vals, Ks, Vv, gam, ws, usb, out);
    mid<<<576, 256, 0, stream>>>(usb, Qs, part, OpartUS, lpart);
    post<<<2576, 256, 0, stream>>>(part, Spart, usb, OpartUS, lpart, out);
}